// Round 6
// baseline (306.168 us; speedup 1.0000x reference)
//
#include <hip/hip_runtime.h>

typedef __attribute__((ext_vector_type(8))) __bf16 bf16x8;
typedef __attribute__((ext_vector_type(4))) float f32x4;

constexpr int Bsz   = 128;
constexpr int EE    = 200;
constexpr int NMASK = 192;
constexpr int PE    = 768;
constexpr int M1    = Bsz * 64;     // 8192 visible rows
constexpr long IMG_ELEMS = (long)Bsz * 3 * 256 * 256;

constexpr int VROWS = 16;           // rows per visible mega-block
constexpr int VBLK  = M1 / VROWS;   // 512 visible blocks
constexpr int FBLK  = NMASK * 4;    // 768 fold blocks (patch x 32-batch group)
constexpr int ASTR  = 776;          // As LDS stride (768+8)

__device__ __forceinline__ f32x4 mfma16(bf16x8 a, bf16x8 b, f32x4 c) {
    return __builtin_amdgcn_mfma_f32_16x16x32_bf16(a, b, c, 0, 0, 0);
}

// ---------------------------------------------------------------------------
// prep1 (no intra-kernel deps, reads only raw inputs):
//   blocks [0,200):   W2D[e][p] = sum_f Wenc[e][f] * Wdec[f][p]          (f32)
//   blocks [200,456): T[n][p]   = ((cb+pos_n)Wenc + benc + pos_n)Wdec+bd (f32)
//   blocks [456,648): dec_masked[i][p] = (mask_token+pos_n)Wdec + bd     (f32)
//   block  648:       masked_idx output
// ---------------------------------------------------------------------------
__global__ __launch_bounds__(256) void k_prep1(
    const float* __restrict__ pos, const float* __restrict__ Wenc,
    const float* __restrict__ Wdec, const float* __restrict__ conv_b,
    const float* __restrict__ b_enc, const float* __restrict__ b_dec,
    const float* __restrict__ mask_token, const int* __restrict__ perm,
    float* __restrict__ W2D, float* __restrict__ T,
    float* __restrict__ dec_masked, float* __restrict__ out_idx)
{
    __shared__ float u[256];
    __shared__ float v[256];
    int blk = blockIdx.x, t = threadIdx.x;

    if (blk < 200) {                       // ---- W2D row e ----
        const int e = blk;
        if (t < EE) u[t] = Wenc[e * EE + t];
        __syncthreads();
        float a0 = 0.f, a1 = 0.f, a2 = 0.f;
        #pragma unroll 4
        for (int f = 0; f < EE; ++f) {
            const float w = u[f];
            a0 = fmaf(w, Wdec[f * PE + t],       a0);
            a1 = fmaf(w, Wdec[f * PE + t + 256], a1);
            a2 = fmaf(w, Wdec[f * PE + t + 512], a2);
        }
        W2D[e * PE + t]       = a0;
        W2D[e * PE + t + 256] = a1;
        W2D[e * PE + t + 512] = a2;
        return;
    }
    blk -= 200;
    if (blk < 256) {                       // ---- T row n ----
        const int n = blk;
        if (t < EE) u[t] = conv_b[t] + pos[n * EE + t];
        __syncthreads();
        if (t < EE) {                      // v'[f] = u.Wenc[:,f] + benc + pos
            float a = 0.f;
            #pragma unroll 4
            for (int e = 0; e < EE; ++e)
                a = fmaf(u[e], Wenc[e * EE + t], a);
            v[t] = a + b_enc[t] + pos[n * EE + t];
        }
        __syncthreads();
        float a0 = b_dec[t], a1 = b_dec[t + 256], a2 = b_dec[t + 512];
        #pragma unroll 4
        for (int f = 0; f < EE; ++f) {
            const float w = v[f];
            a0 = fmaf(w, Wdec[f * PE + t],       a0);
            a1 = fmaf(w, Wdec[f * PE + t + 256], a1);
            a2 = fmaf(w, Wdec[f * PE + t + 512], a2);
        }
        T[n * PE + t]       = a0;
        T[n * PE + t + 256] = a1;
        T[n * PE + t + 512] = a2;
        return;
    }
    blk -= 256;
    if (blk < NMASK) {                     // ---- masked decoder rows ----
        const int i = blk;
        const int n = perm[i];
        u[t] = (t < EE) ? (mask_token[t] + pos[n * EE + t]) : 0.f;
        __syncthreads();
        float a0 = b_dec[t], a1 = b_dec[t + 256], a2 = b_dec[t + 512];
        #pragma unroll 4
        for (int k = 0; k < EE; ++k) {
            const float rv = u[k];
            a0 = fmaf(rv, Wdec[k * PE + t],       a0);
            a1 = fmaf(rv, Wdec[k * PE + t + 256], a1);
            a2 = fmaf(rv, Wdec[k * PE + t + 512], a2);
        }
        dec_masked[i * PE + t]       = a0;
        dec_masked[i * PE + t + 256] = a1;
        dec_masked[i * PE + t + 512] = a2;
        return;
    }
    if (t < NMASK) out_idx[t] = (float)perm[t];
}

// ---------------------------------------------------------------------------
// prep2 (depends on W2D): W123t[p][k] = (bf16) sum_e wflat[e][k] * W2D[e][p]
// n-major [768][768] bf16 so the mega K-loop reads contiguous rows.
// ---------------------------------------------------------------------------
__global__ __launch_bounds__(256) void k_prep2(
    const float* __restrict__ wflat, const float* __restrict__ W2D,
    __bf16* __restrict__ W123t)
{
    __shared__ float colv[256];
    const int p = blockIdx.x, t = threadIdx.x;
    if (t < EE) colv[t] = W2D[t * PE + p];   // column p (one scattered load/thread)
    __syncthreads();
    float a0 = 0.f, a1 = 0.f, a2 = 0.f;
    #pragma unroll 4
    for (int e = 0; e < EE; ++e) {
        const float w = colv[e];
        a0 = fmaf(w, wflat[e * PE + t],       a0);
        a1 = fmaf(w, wflat[e * PE + t + 256], a1);
        a2 = fmaf(w, wflat[e * PE + t + 512], a2);
    }
    W123t[p * PE + t]       = (__bf16)a0;
    W123t[p * PE + t + 256] = (__bf16)a1;
    W123t[p * PE + t + 512] = (__bf16)a2;
}

// ---------------------------------------------------------------------------
// Mega kernel. 1280 blocks:
//   blocks [0, 768):    fold — broadcast masked rows (dec_masked from prep1)
//                       to all batches. Pure nt stores; dispatched FIRST so
//                       the 75 MB write drain overlaps the compute blocks.
//   blocks [768, 1280): visible 16-row tiles: stage patch A (f32->bf16, nt),
//                       ONE K=768 GEMM vs W123t, add T[n], scatter to img.
// Per K-step: 1 ds_read + 6 independent B loads (single wait) + 6 MFMA.
// ---------------------------------------------------------------------------
__global__ __launch_bounds__(512, 4) void k_mega(
    const float* __restrict__ x, const __bf16* __restrict__ W123t,
    const float* __restrict__ T, const int* __restrict__ perm,
    const float* __restrict__ dec_masked, float* __restrict__ img)
{
    __shared__ __bf16 As[VROWS * ASTR];    // 24832 B
    __shared__ int nidx[VROWS];

    const int t    = threadIdx.x;
    const int lane = t & 63, wid = t >> 6;        // 8 waves
    const int quad = lane >> 4, lid = lane & 15;

    if (blockIdx.x < FBLK) {
        // ---------------- fold path ----------------
        const int fb  = blockIdx.x;
        const int i   = fb % NMASK;               // masked patch slot
        const int grp = fb / NMASK;               // batches [grp*32, grp*32+32)
        const int n   = perm[i];
        if (t < 384) {
            const int sub = t / 192, f4 = t % 192;
            f32x4 v = *(const f32x4*)&dec_masked[i * PE + f4 * 4];
            const int p = f4 * 4;
            const int c = p >> 8, py = (p >> 4) & 15, px = p & 15;
            const long base = (long)c * 65536 + ((n >> 4) * 16 + py) * 256
                            + (n & 15) * 16 + px;
            const int b0 = grp * 32 + sub * 16;
            #pragma unroll
            for (int bb = 0; bb < 16; ++bb)
                __builtin_nontemporal_store(
                    v, (f32x4*)&img[(long)(b0 + bb) * 3 * 65536 + base]);
        }
        return;
    }

    // ---------------- visible path ----------------
    const int bid  = blockIdx.x - FBLK;    // 0..511
    const int m0   = bid * VROWS;
    const int bimg = m0 >> 6;
    if (t < VROWS) nidx[t] = perm[NMASK + (m0 & 63) + t];

    // phase 0: stage A tile (16 x 768) from x, f32 -> bf16 (nt loads)
    {
        const int row = t >> 5;            // 16 rows x 32 threads
        const int tt  = t & 31;
        const int m = m0 + row;
        const int n = perm[NMASK + (m & 63)];
        const int abase = bimg * 196608 + (n >> 4) * 4096 + (n & 15) * 16;
        #pragma unroll
        for (int it = 0; it < 3; ++it) {
            int k = tt * 8 + it * 256;
            int c = k >> 8, py = (k >> 4) & 15, px = k & 15;
            const float* ap = x + abase + c * 65536 + py * 256 + px;
            f32x4 a0 = __builtin_nontemporal_load((const f32x4*)ap);
            f32x4 a1 = __builtin_nontemporal_load((const f32x4*)(ap + 4));
            bf16x8 av;
            av[0] = (__bf16)a0.x; av[1] = (__bf16)a0.y; av[2] = (__bf16)a0.z; av[3] = (__bf16)a0.w;
            av[4] = (__bf16)a1.x; av[5] = (__bf16)a1.y; av[6] = (__bf16)a1.z; av[7] = (__bf16)a1.w;
            *(bf16x8*)&As[row * ASTR + k] = av;
        }
    }
    __syncthreads();

    // single GEMM: 16 x 768 = A(16x768) . W123t^T   (barrier-free K-loop)
    const int p0w = wid * 96;
    f32x4 acc[6] = {};
    const __bf16* bp0 = &W123t[(p0w + 0 * 16 + lid) * PE + quad * 8];
    const __bf16* bp1 = &W123t[(p0w + 1 * 16 + lid) * PE + quad * 8];
    const __bf16* bp2 = &W123t[(p0w + 2 * 16 + lid) * PE + quad * 8];
    const __bf16* bp3 = &W123t[(p0w + 3 * 16 + lid) * PE + quad * 8];
    const __bf16* bp4 = &W123t[(p0w + 4 * 16 + lid) * PE + quad * 8];
    const __bf16* bp5 = &W123t[(p0w + 5 * 16 + lid) * PE + quad * 8];
    #pragma unroll 2
    for (int k0 = 0; k0 < PE; k0 += 32) {
        bf16x8 a0 = *(const bf16x8*)&As[lid * ASTR + k0 + quad * 8];
        bf16x8 b0 = *(const bf16x8*)&bp0[k0];
        bf16x8 b1 = *(const bf16x8*)&bp1[k0];
        bf16x8 b2 = *(const bf16x8*)&bp2[k0];
        bf16x8 b3 = *(const bf16x8*)&bp3[k0];
        bf16x8 b4 = *(const bf16x8*)&bp4[k0];
        bf16x8 b5 = *(const bf16x8*)&bp5[k0];
        acc[0] = mfma16(a0, b0, acc[0]);
        acc[1] = mfma16(a0, b1, acc[1]);
        acc[2] = mfma16(a0, b2, acc[2]);
        acc[3] = mfma16(a0, b3, acc[3]);
        acc[4] = mfma16(a0, b4, acc[4]);
        acc[5] = mfma16(a0, b5, acc[5]);
    }

    // epilogue: dec = acc + T[n][p]; scatter to img (nt stores)
    #pragma unroll
    for (int j = 0; j < 6; ++j) {
        const int p = p0w + j * 16 + lid;
        const int c = p >> 8, py = (p >> 4) & 15, px = p & 15;
        const long obase = (long)(bimg * 3 + c) * 65536 + py * 256 + px;
        #pragma unroll
        for (int r = 0; r < 4; ++r) {
            const int n = nidx[quad * 4 + r];
            const float v = acc[j][r] + T[n * PE + p];
            __builtin_nontemporal_store(
                v, &img[obase + (n >> 4) * 4096 + (n & 15) * 16]);
        }
    }
}

// ---------------------------------------------------------------------------
extern "C" void kernel_launch(void* const* d_in, const int* in_sizes, int n_in,
                              void* d_out, int out_size, void* d_ws, size_t ws_size,
                              hipStream_t stream)
{
    const float* x          = (const float*)d_in[0];
    const float* conv_w     = (const float*)d_in[1];
    const float* conv_b     = (const float*)d_in[2];
    const float* pos        = (const float*)d_in[3];
    const float* mask_token = (const float*)d_in[4];
    const float* W_enc      = (const float*)d_in[5];
    const float* b_enc      = (const float*)d_in[6];
    const float* W_dec      = (const float*)d_in[7];
    const float* b_dec      = (const float*)d_in[8];
    const int*   perm       = (const int*)d_in[9];
    float* out = (float*)d_out;

    // workspace carve-up (16B-aligned)
    __bf16* W123t = (__bf16*)d_ws;                 // 768*768 bf16 (1.18 MB)
    float*  W2D   = (float*)(W123t + PE * PE);     // 200*768 f32
    float*  T     = W2D + EE * PE;                 // 256*768 f32
    float*  decm  = T + 256 * PE;                  // 192*768 f32

    k_prep1<<<200 + 256 + NMASK + 1, 256, 0, stream>>>(
        pos, W_enc, W_dec, conv_b, b_enc, b_dec, mask_token, perm,
        W2D, T, decm, out + IMG_ELEMS);
    k_prep2<<<PE, 256, 0, stream>>>(conv_w, W2D, W123t);
    k_mega<<<FBLK + VBLK, 512, 0, stream>>>(
        x, W123t, T, perm, decm, out);
}